// Round 3
// baseline (809.480 us; speedup 1.0000x reference)
//
#include <hip/hip_runtime.h>

// ---------------------------------------------------------------------------
// TransformerBlock: out = LN( FFN(X) + X ),  X = LN( Q + softmax(QK^T/s) V )
// B=32, SQ=SK=D=1024.  bf16 MFMA GEMMs (fp32 accum, 256^2 8-phase schedule,
// persistent 2-tile blocks), fp32 softmax/LN, fused residual epilogues.
// ---------------------------------------------------------------------------

typedef __attribute__((ext_vector_type(8))) short bf16x8;
typedef __attribute__((ext_vector_type(4))) float f32x4;

__device__ __forceinline__ unsigned short f2bf(float f) {
  union { float f; unsigned u; } x; x.f = f;
  unsigned r = x.u + 0x7fffu + ((x.u >> 16) & 1u);  // round-to-nearest-even
  return (unsigned short)(r >> 16);
}
__device__ __forceinline__ float bf2f(unsigned short u) {
  union { unsigned u; float f; } x; x.u = (unsigned)u << 16;
  return x.f;
}

// ---------------- cast f32 -> bf16 (vectorized, grid-stride) ----------------
__global__ __launch_bounds__(256) void cast_kernel(const float* __restrict__ in,
                                                   unsigned short* __restrict__ out,
                                                   long n) {
  long stride = (long)gridDim.x * blockDim.x * 4;
  for (long e = ((long)blockIdx.x * blockDim.x + threadIdx.x) * 4; e < n; e += stride) {
    float4 v = *(const float4*)(in + e);
    ushort4 o;
    o.x = f2bf(v.x); o.y = f2bf(v.y); o.z = f2bf(v.z); o.w = f2bf(v.w);
    *(ushort4*)(out + e) = o;
  }
}

// ---------------- per-batch transpose + cast: Vt[b][d][k] = bf16(V[b][k][d]) ----
__global__ __launch_bounds__(256) void transpose_cast_kernel(const float* __restrict__ V,
                                                             unsigned short* __restrict__ Vt) {
  __shared__ unsigned short tile[32][33];
  const int b = blockIdx.z;
  const float* Vb = V + (size_t)b * 1024 * 1024;
  unsigned short* Vtb = Vt + (size_t)b * 1024 * 1024;
  const int d0 = blockIdx.x * 32, k0 = blockIdx.y * 32;
  const int c = threadIdx.x & 31, rq = threadIdx.x >> 5;
#pragma unroll
  for (int i = 0; i < 4; ++i) {
    int r = rq * 4 + i;
    tile[r][c] = f2bf(Vb[(size_t)(k0 + r) * 1024 + d0 + c]);
  }
  __syncthreads();
#pragma unroll
  for (int i = 0; i < 4; ++i) {
    int r = rq * 4 + i;
    Vtb[(size_t)(d0 + r) * 1024 + k0 + c] = tile[c][r];
  }
}

// ---------------------------------------------------------------------------
// GEMM: C = A @ B^T  (A:[M][K], B:[N][K] row-major bf16), N = 1024 lanes wide.
// Persistent: each block computes TWO 256x256 tiles sharing the A-panel
// (bx and bx+2), K-loop runs 2*(K/64) tiles continuously with a mid-loop
// epilogue. 8 waves (2Mx4N), 8-phase schedule, counted vmcnt(4), T2 swizzle,
// T5 setprio, T1 XCD swizzle.
// EPI: 4 = C_bf16 = acc*scale
//      1 = C_f32  = acc + resf          (residual f32)
//      2 = C_bf16 = relu(acc + bias)
//      5 = C_f32  = acc + bias + resb   (residual bf16)
// ---------------------------------------------------------------------------
template <int EPI>
__global__ __launch_bounds__(512, 2) void gemm8(
    const unsigned short* __restrict__ A, const unsigned short* __restrict__ B,
    const float* __restrict__ bias, const float* __restrict__ resf,
    const unsigned short* __restrict__ resb, void* __restrict__ Cout,
    int N, int K, long sA, long sB, long sC, float scale, int gxy2) {

  __shared__ unsigned short ldsA[2][16384];  // [buf][256 rows x 64 cols]
  __shared__ unsigned short ldsB[2][16384];

  // bijective XCD swizzle (grid = 256, %8 == 0)
  const int nwg = gridDim.x;
  const int orig = blockIdx.x;
  const int wg = (orig & 7) * (nwg >> 3) + (orig >> 3);
  const int bz = wg / gxy2;
  const int rem = wg - bz * gxy2;
  const int by = rem >> 1;
  const int bxh = rem & 1;

  A += (size_t)bz * sA;
  B += (size_t)bz * sB;
  const size_t cbase = (size_t)bz * sC;
  const int brow = by * 256;
  const int bcol0 = bxh * 256, bcol1 = bxh * 256 + 512;

  const int tid = threadIdx.x;
  const int wave = tid >> 6, lane = tid & 63;
  const int wm = wave >> 2, wn = wave & 3;   // 2 x 4 wave grid
  const int lr = lane & 15, kh = lane >> 4;
  const int swz = (lane & 7) << 4;

  // staging: 8KB per load; lane covers row wave*8+(lane>>3), pre-swizzled col
  const int s_r = wave * 8 + (lane >> 3);
  const int s_c = ((lane & 7) ^ (lane >> 3)) * 8;

  // kt: global K-tile index in [0, 2*K/64). Tile sel = kt>=nkt uses bcol1 (B only;
  // A is shared between the two output tiles).
  const int nkt = K >> 6;
  auto stg = [&](int mat, int kt, int h) {
    const int kcol = (kt >= nkt ? (kt - nkt) : kt) * 64;
    const unsigned short* base =
        mat ? (B + (size_t)(kt >= nkt ? bcol1 : bcol0) * K + kcol)
            : (A + (size_t)brow * K + kcol);
    unsigned short* region = mat ? ldsB[kt & 1] : ldsA[kt & 1];
#pragma unroll
    for (int j = 0; j < 2; ++j) {
      const unsigned short* src = base + (size_t)(h * 128 + j * 64 + s_r) * K + s_c;
      unsigned short* dst = region + h * 8192 + j * 4096 + wave * 512;  // wave-uniform
      __builtin_amdgcn_global_load_lds(
          (const __attribute__((address_space(1))) void*)src,
          (__attribute__((address_space(3))) void*)dst, 16, 0, 0);
    }
  };

  auto rdA = [&](int c, int m, int k) -> bf16x8 {
    const int r = wm * 128 + m * 16 + lr;
    const int off = r * 128 + ((k * 64 + kh * 16) ^ swz);
    return *(const bf16x8*)((const char*)ldsA[c] + off);
  };
  auto rdB = [&](int c, int n, int k) -> bf16x8 {
    const int r = wn * 64 + n * 16 + lr;
    const int off = r * 128 + ((k * 64 + kh * 16) ^ swz);
    return *(const bf16x8*)((const char*)ldsB[c] + off);
  };

  f32x4 acc[8][4];
#pragma unroll
  for (int m = 0; m < 8; ++m)
#pragma unroll
    for (int n = 0; n < 4; ++n)
#pragma unroll
      for (int i = 0; i < 4; ++i) acc[m][n][i] = 0.f;

  auto epi = [&](int sel) {
    const int bc = sel ? bcol1 : bcol0;
#pragma unroll
    for (int m = 0; m < 8; ++m) {
#pragma unroll
      for (int n = 0; n < 4; ++n) {
        const int c0 = bc + wn * 64 + n * 16 + lr;
#pragma unroll
        for (int i = 0; i < 4; ++i) {
          const int r0 = brow + wm * 128 + m * 16 + kh * 4 + i;
          const size_t idx = cbase + (size_t)r0 * N + c0;
          float v = acc[m][n][i];
          if (EPI == 4) {
            ((unsigned short*)Cout)[idx] = f2bf(v * scale);
          } else if (EPI == 1) {
            ((float*)Cout)[idx] = v + resf[idx];
          } else if (EPI == 2) {
            v += bias[c0];
            ((unsigned short*)Cout)[idx] = f2bf(fmaxf(v, 0.f));
          } else {  // EPI == 5
            v += bias[c0] + bf2f(resb[idx]);
            ((float*)Cout)[idx] = v;
          }
        }
      }
    }
  };

  const int TT = nkt * 2;   // total K-tiles across both output tiles
  const int nI = TT >> 1;   // iterations (2 K-tiles each)
  const int half = nI >> 1; // tile boundary

  // prologue: A(0), B(0), B(1) — 12 loads; leave newest 4 (B1) in flight
  stg(0, 0, 0); stg(0, 0, 1);
  stg(1, 0, 0); stg(1, 0, 1);
  stg(1, 1, 0); stg(1, 1, 1);
  asm volatile("s_waitcnt vmcnt(4)" ::: "memory");
  asm volatile("s_barrier" ::: "memory");

  bf16x8 bfrag[4][2];

  for (int I = 0; I < nI; ++I) {
    if (I == half) {  // tile-0 epilogue; pipeline (loads for tile 1) stays warm
      epi(0);
#pragma unroll
      for (int m = 0; m < 8; ++m)
#pragma unroll
        for (int n = 0; n < 4; ++n)
#pragma unroll
          for (int i = 0; i < 4; ++i) acc[m][n][i] = 0.f;
    }
    const bool nl = (I + 1 < nI);
#pragma unroll
    for (int g = 0; g < 2; ++g) {          // K-tile 2I+g lives in buf g
#pragma unroll
      for (int q = 0; q < 4; ++q) {        // quadrant: A-frags m = 2q, 2q+1
        const int p = g * 4 + q;

        // ---- ds_read register subtile ----
        if (q == 0) {
#pragma unroll
          for (int n = 0; n < 4; ++n)
#pragma unroll
            for (int k = 0; k < 2; ++k) bfrag[n][k] = rdB(g, n, k);
        }
        bf16x8 afr[2][2];
#pragma unroll
        for (int mm = 0; mm < 2; ++mm)
#pragma unroll
          for (int k = 0; k < 2; ++k) afr[mm][k] = rdA(g, q * 2 + mm, k);

        // ---- stage schedule (each region's last read >=1 barrier earlier) ----
        if (p == 0) stg(0, 2 * I + 1, 0);
        if (p == 1) { stg(0, 2 * I + 1, 1); if (nl) stg(1, 2 * I + 2, 0); }
        if (p == 2) { if (nl) stg(1, 2 * I + 2, 1); }
        if (p == 4) { if (nl) stg(0, 2 * I + 2, 0); }
        if (p == 5) { if (nl) stg(0, 2 * I + 2, 1); }
        if (p == 6) { if (nl) stg(1, 2 * I + 3, 0); }
        if (p == 7) { if (nl) stg(1, 2 * I + 3, 1); }

        asm volatile("s_barrier" ::: "memory");  // barrier1 (no vmem drain)

        __builtin_amdgcn_s_setprio(1);
#pragma unroll
        for (int k = 0; k < 2; ++k)              // k outermost: dep distance 8
#pragma unroll
          for (int mm = 0; mm < 2; ++mm)
#pragma unroll
            for (int n = 0; n < 4; ++n)
              acc[q * 2 + mm][n] = __builtin_amdgcn_mfma_f32_16x16x32_bf16(
                  afr[mm][k], bfrag[n][k], acc[q * 2 + mm][n], 0, 0, 0);
        __builtin_amdgcn_s_setprio(0);

        // counted waits once per K-tile (phases 4 & 8); drain on final pair
        if (q == 3) {
          if (g == 0 && !nl) asm volatile("s_waitcnt vmcnt(0)" ::: "memory");
          else               asm volatile("s_waitcnt vmcnt(4)" ::: "memory");
        }
        asm volatile("s_barrier" ::: "memory");  // barrier2
      }
    }
  }

  epi(1);
}

// ---------------- row softmax (in-place): P = softmax(S), bf16 -------------
__global__ __launch_bounds__(256) void softmax_kernel(unsigned short* __restrict__ S) {
  __shared__ float red[4];
  const size_t row = blockIdx.x;
  const int t = threadIdx.x;
  ushort4 u = *(const ushort4*)(S + row * 1024 + t * 4);
  float v0 = bf2f(u.x), v1 = bf2f(u.y), v2 = bf2f(u.z), v3 = bf2f(u.w);
  float mx = fmaxf(fmaxf(v0, v1), fmaxf(v2, v3));
#pragma unroll
  for (int o = 32; o; o >>= 1) mx = fmaxf(mx, __shfl_xor(mx, o));
  if ((t & 63) == 0) red[t >> 6] = mx;
  __syncthreads();
  mx = fmaxf(fmaxf(red[0], red[1]), fmaxf(red[2], red[3]));
  __syncthreads();
  float e0 = __expf(v0 - mx), e1 = __expf(v1 - mx);
  float e2 = __expf(v2 - mx), e3 = __expf(v3 - mx);
  float s = e0 + e1 + e2 + e3;
#pragma unroll
  for (int o = 32; o; o >>= 1) s += __shfl_xor(s, o);
  if ((t & 63) == 0) red[t >> 6] = s;
  __syncthreads();
  s = red[0] + red[1] + red[2] + red[3];
  const float inv = 1.f / s;
  ushort4 o4;
  o4.x = f2bf(e0 * inv); o4.y = f2bf(e1 * inv);
  o4.z = f2bf(e2 * inv); o4.w = f2bf(e3 * inv);
  *(ushort4*)(S + row * 1024 + t * 4) = o4;
}

// ---------------- LayerNorm over rows of 1024 (single input) ----------------
// out = LN(A); writes fp32 (Xf, in-place safe) and/or bf16 (Xb).
__global__ __launch_bounds__(256) void ln_kernel(
    const float* __restrict__ A,
    const float* __restrict__ gamma, const float* __restrict__ beta,
    float* __restrict__ Xf, unsigned short* __restrict__ Xb) {
  __shared__ float red[4];
  const size_t row = blockIdx.x;
  const int t = threadIdx.x;
  float4 va = *(const float4*)(A + row * 1024 + t * 4);
  float x0 = va.x, x1 = va.y, x2 = va.z, x3 = va.w;
  float s = x0 + x1 + x2 + x3;
  float q = x0 * x0 + x1 * x1 + x2 * x2 + x3 * x3;
#pragma unroll
  for (int o = 32; o; o >>= 1) { s += __shfl_xor(s, o); q += __shfl_xor(q, o); }
  if ((t & 63) == 0) red[t >> 6] = s;
  __syncthreads();
  s = red[0] + red[1] + red[2] + red[3];
  __syncthreads();
  if ((t & 63) == 0) red[t >> 6] = q;
  __syncthreads();
  q = red[0] + red[1] + red[2] + red[3];
  const float mu = s * (1.f / 1024.f);
  const float var = q * (1.f / 1024.f) - mu * mu;
  const float rs = rsqrtf(var + 1e-5f);
  float4 g = *(const float4*)(gamma + t * 4);
  float4 be = *(const float4*)(beta + t * 4);
  float o0 = (x0 - mu) * rs * g.x + be.x;
  float o1 = (x1 - mu) * rs * g.y + be.y;
  float o2 = (x2 - mu) * rs * g.z + be.z;
  float o3 = (x3 - mu) * rs * g.w + be.w;
  if (Xf) {
    float4 o; o.x = o0; o.y = o1; o.z = o2; o.w = o3;
    *(float4*)(Xf + row * 1024 + t * 4) = o;
  }
  if (Xb) {
    ushort4 u; u.x = f2bf(o0); u.y = f2bf(o1); u.z = f2bf(o2); u.w = f2bf(o3);
    *(ushort4*)(Xb + row * 1024 + t * 4) = u;
  }
}

// ---------------------------------------------------------------------------
extern "C" void kernel_launch(void* const* d_in, const int* in_sizes, int n_in,
                              void* d_out, int out_size, void* d_ws, size_t ws_size,
                              hipStream_t stream) {
  const float* Q    = (const float*)d_in[0];
  const float* Km   = (const float*)d_in[1];
  const float* V    = (const float*)d_in[2];
  const float* W1   = (const float*)d_in[3];
  const float* b1   = (const float*)d_in[4];
  const float* W2   = (const float*)d_in[5];
  const float* b2   = (const float*)d_in[6];
  const float* gamma = (const float*)d_in[7];
  const float* beta  = (const float*)d_in[8];
  float* out = (float*)d_out;

  // workspace layout (MB):
  //  [0,64)    Qb bf16        -> later VA f32 spans [0,128)
  //  [64,128)  Kb bf16
  //  [128,192) Vtb bf16       -> later Xb bf16
  //  [192,256) Sb bf16 (scores, softmax in-place -> P) -> later Hb bf16
  //  [256,260) W1b, W2b bf16
  char* ws = (char*)d_ws;
  const size_t NEL = (size_t)32 * 1024 * 1024;
  unsigned short* Qb  = (unsigned short*)ws;
  unsigned short* Kb  = Qb + NEL;
  unsigned short* Vtb = Kb + NEL;
  unsigned short* Sb  = Vtb + NEL;
  unsigned short* W1b = Sb + NEL;
  unsigned short* W2b = W1b + 1024 * 1024;
  float*          VA = (float*)ws;  // aliases Qb+Kb (dead after GEMM1)
  unsigned short* Xb = Vtb;         // alias (Vtb dead after GEMM2)
  unsigned short* Hb = Sb;          // alias (P dead after GEMM2)

  const long M1 = 1024L * 1024L;
  const float scale = 1.0f / (sqrtf(1024.0f) + 1e-8f);

  cast_kernel<<<4096, 256, 0, stream>>>(Q, Qb, (long)NEL);
  cast_kernel<<<4096, 256, 0, stream>>>(Km, Kb, (long)NEL);
  cast_kernel<<<64, 256, 0, stream>>>(W1, W1b, 1024 * 1024);
  cast_kernel<<<64, 256, 0, stream>>>(W2, W2b, 1024 * 1024);
  transpose_cast_kernel<<<dim3(32, 32, 32), 256, 0, stream>>>(V, Vtb);

  // Sb = bf16((Q K^T) * scale)   [gxy2 = 4by x 2bxh = 8 per batch]
  gemm8<4><<<256, 512, 0, stream>>>(Qb, Kb, nullptr, nullptr, nullptr, Sb,
                                    1024, 1024, M1, M1, M1, scale, 8);
  softmax_kernel<<<32768, 256, 0, stream>>>(Sb);
  // VA = P @ Vt^T + Q   (residual fused)
  gemm8<1><<<256, 512, 0, stream>>>(Sb, Vtb, nullptr, Q, nullptr, VA,
                                    1024, 1024, M1, M1, M1, 1.0f, 8);
  // Xb = bf16(LN(VA))
  ln_kernel<<<32768, 256, 0, stream>>>(VA, gamma, beta, nullptr, Xb);
  // Hb = bf16(relu(Xb @ W1^T + b1))   [M=32768: gxy2 = 128by x 2bxh = 256]
  gemm8<2><<<256, 512, 0, stream>>>(Xb, W1b, b1, nullptr, nullptr, Hb,
                                    1024, 1024, 0, 0, 0, 1.0f, 256);
  // out = Hb @ W2^T + b2 + Xb   (residual fused, fp32)
  gemm8<5><<<256, 512, 0, stream>>>(Hb, W2b, b2, nullptr, Xb, out,
                                    1024, 1024, 0, 0, 0, 1.0f, 256);
  // out = LN(out) in-place
  ln_kernel<<<32768, 256, 0, stream>>>(out, gamma, beta, out, nullptr);
}

// Round 4
// 531.893 us; speedup vs baseline: 1.5219x; 1.5219x over previous
//
#include <hip/hip_runtime.h>

// ---------------------------------------------------------------------------
// TransformerBlock: out = LN( FFN(X) + X ),  X = LN( Q + softmax(QK^T/s) V )
// B=32, SQ=SK=D=1024.  bf16 MFMA GEMMs (fp32 accum, 256^2 8-phase schedule),
// LDS-vectorized bf16 epilogues with fused bias/residual, fp32 softmax/LN.
// ---------------------------------------------------------------------------

typedef __attribute__((ext_vector_type(8))) short bf16x8;
typedef __attribute__((ext_vector_type(4))) float f32x4;

__device__ __forceinline__ unsigned short f2bf(float f) {
  union { float f; unsigned u; } x; x.f = f;
  unsigned r = x.u + 0x7fffu + ((x.u >> 16) & 1u);  // round-to-nearest-even
  return (unsigned short)(r >> 16);
}
__device__ __forceinline__ float bf2f(unsigned short u) {
  union { unsigned u; float f; } x; x.u = (unsigned)u << 16;
  return x.f;
}

// ---------------- cast f32 -> bf16 (vectorized, grid-stride) ----------------
__global__ __launch_bounds__(256) void cast_kernel(const float* __restrict__ in,
                                                   unsigned short* __restrict__ out,
                                                   long n) {
  long stride = (long)gridDim.x * blockDim.x * 4;
  for (long e = ((long)blockIdx.x * blockDim.x + threadIdx.x) * 4; e < n; e += stride) {
    float4 v = *(const float4*)(in + e);
    ushort4 o;
    o.x = f2bf(v.x); o.y = f2bf(v.y); o.z = f2bf(v.z); o.w = f2bf(v.w);
    *(ushort4*)(out + e) = o;
  }
}

// ---------------- per-batch transpose + cast: Vt[b][d][k] = bf16(V[b][k][d]) ----
__global__ __launch_bounds__(256) void transpose_cast_kernel(const float* __restrict__ V,
                                                             unsigned short* __restrict__ Vt) {
  __shared__ unsigned short tile[32][33];
  const int b = blockIdx.z;
  const float* Vb = V + (size_t)b * 1024 * 1024;
  unsigned short* Vtb = Vt + (size_t)b * 1024 * 1024;
  const int d0 = blockIdx.x * 32, k0 = blockIdx.y * 32;
  const int c = threadIdx.x & 31, rq = threadIdx.x >> 5;
#pragma unroll
  for (int i = 0; i < 4; ++i) {
    int r = rq * 4 + i;
    tile[r][c] = f2bf(Vb[(size_t)(k0 + r) * 1024 + d0 + c]);
  }
  __syncthreads();
#pragma unroll
  for (int i = 0; i < 4; ++i) {
    int r = rq * 4 + i;
    Vtb[(size_t)(d0 + r) * 1024 + k0 + c] = tile[c][r];
  }
}

// ---------------------------------------------------------------------------
// GEMM: C_bf16 = epi(A @ B^T)  (A:[M][K], B:[N][K] row-major bf16)
// 256x256 tile, BK=64, 8 waves (2Mx4N), 8-phase schedule, counted vmcnt(4),
// T2 XOR-swizzle both-sides, T5 setprio, T1 XCD swizzle, LDS-staged epilogue.
// EPI: 4 = acc*scale ; 6 = acc+resb ; 2 = relu(acc+bias) ; 7 = acc+bias+resb
// ---------------------------------------------------------------------------
template <int EPI>
__global__ __launch_bounds__(512, 2) void gemm8(
    const unsigned short* __restrict__ A, const unsigned short* __restrict__ B,
    const float* __restrict__ bias, const unsigned short* __restrict__ resb,
    unsigned short* __restrict__ Cout,
    int N, int K, long sA, long sB, long sC, float scale, int gx, int gxy) {

  __shared__ char smem[131072];  // K-loop: A/B double-buffers. Epilogue: fp32 stage.

  // bijective XCD swizzle (grid = 512, %8 == 0)
  const int nwg = gridDim.x;
  const int orig = blockIdx.x;
  const int wg = (orig & 7) * (nwg >> 3) + (orig >> 3);
  const int bz = wg / gxy;
  const int rem = wg - bz * gxy;
  const int by = rem / gx;
  const int bx = rem - by * gx;

  A += (size_t)bz * sA;
  B += (size_t)bz * sB;
  const size_t cbase = (size_t)bz * sC;
  const int brow = by * 256, bcol = bx * 256;

  const int tid = threadIdx.x;
  const int wave = tid >> 6, lane = tid & 63;
  const int wm = wave >> 2, wn = wave & 3;   // 2 x 4 wave grid
  const int lr = lane & 15, kh = lane >> 4;
  const int swz = (lane & 7) << 4;

  // staging: 8KB per call; lane covers row wave*8+(lane>>3), pre-swizzled col
  const int s_r = wave * 8 + (lane >> 3);
  const int s_c = ((lane & 7) ^ (lane >> 3)) * 8;

  auto stg = [&](const unsigned short* g, int rowbase, int kt, int h, int mat) {
    char* region = smem + mat * 65536 + (kt & 1) * 32768;
#pragma unroll
    for (int j = 0; j < 2; ++j) {
      const unsigned short* src =
          g + (size_t)(rowbase + h * 128 + j * 64 + s_r) * K + kt * 64 + s_c;
      char* dst = region + h * 16384 + j * 8192 + wave * 1024;  // wave-uniform
      __builtin_amdgcn_global_load_lds(
          (const __attribute__((address_space(1))) void*)src,
          (__attribute__((address_space(3))) void*)dst, 16, 0, 0);
    }
  };

  auto rdA = [&](int c, int m, int k) -> bf16x8 {
    const int r = wm * 128 + m * 16 + lr;
    const int off = r * 128 + ((k * 64 + kh * 16) ^ swz);
    return *(const bf16x8*)(smem + c * 32768 + off);
  };
  auto rdB = [&](int c, int n, int k) -> bf16x8 {
    const int r = wn * 64 + n * 16 + lr;
    const int off = r * 128 + ((k * 64 + kh * 16) ^ swz);
    return *(const bf16x8*)(smem + 65536 + c * 32768 + off);
  };

  f32x4 acc[8][4];
#pragma unroll
  for (int m = 0; m < 8; ++m)
#pragma unroll
    for (int n = 0; n < 4; ++n)
#pragma unroll
      for (int i = 0; i < 4; ++i) acc[m][n][i] = 0.f;

  const int nkt = K >> 6;   // K-tiles of 64
  const int nI = nkt >> 1;  // 2 tiles per iteration

  // prologue: A(0), B(0), B(1) — 12 loads; leave newest 4 (B1) in flight
  stg(A, brow, 0, 0, 0); stg(A, brow, 0, 1, 0);
  stg(B, bcol, 0, 0, 1); stg(B, bcol, 0, 1, 1);
  stg(B, bcol, 1, 0, 1); stg(B, bcol, 1, 1, 1);
  asm volatile("s_waitcnt vmcnt(4)" ::: "memory");
  asm volatile("s_barrier" ::: "memory");

  bf16x8 bfrag[4][2];

  for (int I = 0; I < nI; ++I) {
    const bool nl = (I + 1 < nI);
#pragma unroll
    for (int g = 0; g < 2; ++g) {          // K-tile 2I+g lives in buf g
#pragma unroll
      for (int q = 0; q < 4; ++q) {        // quadrant: A-frags m = 2q, 2q+1
        const int p = g * 4 + q;

        // ---- ds_read register subtile ----
        if (q == 0) {
#pragma unroll
          for (int n = 0; n < 4; ++n)
#pragma unroll
            for (int k = 0; k < 2; ++k) bfrag[n][k] = rdB(g, n, k);
        }
        bf16x8 afr[2][2];
#pragma unroll
        for (int mm = 0; mm < 2; ++mm)
#pragma unroll
          for (int k = 0; k < 2; ++k) afr[mm][k] = rdA(g, q * 2 + mm, k);

        // ---- stage schedule (each region's last read >=1 barrier earlier) ----
        if (p == 0) stg(A, brow, 2 * I + 1, 0, 0);
        if (p == 1) { stg(A, brow, 2 * I + 1, 1, 0);
                      if (nl) stg(B, bcol, 2 * I + 2, 0, 1); }
        if (p == 2) { if (nl) stg(B, bcol, 2 * I + 2, 1, 1); }
        if (p == 4) { if (nl) stg(A, brow, 2 * I + 2, 0, 0); }
        if (p == 5) { if (nl) stg(A, brow, 2 * I + 2, 1, 0); }
        if (p == 6) { if (nl) stg(B, bcol, 2 * I + 3, 0, 1); }
        if (p == 7) { if (nl) stg(B, bcol, 2 * I + 3, 1, 1); }

        asm volatile("s_barrier" ::: "memory");  // barrier1 (no vmem drain)

        __builtin_amdgcn_s_setprio(1);
#pragma unroll
        for (int k = 0; k < 2; ++k)              // k outermost: dep distance 8
#pragma unroll
          for (int mm = 0; mm < 2; ++mm)
#pragma unroll
            for (int n = 0; n < 4; ++n)
              acc[q * 2 + mm][n] = __builtin_amdgcn_mfma_f32_16x16x32_bf16(
                  afr[mm][k], bfrag[n][k], acc[q * 2 + mm][n], 0, 0, 0);
        __builtin_amdgcn_s_setprio(0);

        // counted waits once per K-tile (phases 4 & 8); drain on final pair
        if (q == 3) {
          if (g == 0 && !nl) asm volatile("s_waitcnt vmcnt(0)" ::: "memory");
          else               asm volatile("s_waitcnt vmcnt(4)" ::: "memory");
        }
        asm volatile("s_barrier" ::: "memory");  // barrier2
      }
    }
  }

  // ---- LDS-staged vectorized epilogue (smem free after final drain) ----
  float* eplds = (float*)smem;  // 128 rows x 256 cols fp32 = 128 KiB
#pragma unroll
  for (int pass = 0; pass < 2; ++pass) {
    __syncthreads();
    if (wm == pass) {
#pragma unroll
      for (int m = 0; m < 8; ++m)
#pragma unroll
        for (int n = 0; n < 4; ++n)
#pragma unroll
          for (int i = 0; i < 4; ++i)
            eplds[(m * 16 + kh * 4 + i) * 256 + wn * 64 + n * 16 + lr] = acc[m][n][i];
    }
    __syncthreads();
#pragma unroll
    for (int j = 0; j < 16; ++j) {
      const int rl = j * 8 + wave;
      const int grow = brow + pass * 128 + rl;
      const int gcol = bcol + lane * 4;
      const size_t idx = cbase + (size_t)grow * N + gcol;
      float4 v = *(const float4*)&eplds[rl * 256 + lane * 4];
      float o0 = v.x, o1 = v.y, o2 = v.z, o3 = v.w;
      if (EPI == 4) {
        o0 *= scale; o1 *= scale; o2 *= scale; o3 *= scale;
      } else if (EPI == 6) {
        ushort4 r = *(const ushort4*)&resb[idx];
        o0 += bf2f(r.x); o1 += bf2f(r.y); o2 += bf2f(r.z); o3 += bf2f(r.w);
      } else if (EPI == 2) {
        float4 bb = *(const float4*)&bias[gcol];
        o0 = fmaxf(o0 + bb.x, 0.f); o1 = fmaxf(o1 + bb.y, 0.f);
        o2 = fmaxf(o2 + bb.z, 0.f); o3 = fmaxf(o3 + bb.w, 0.f);
      } else {  // EPI == 7
        float4 bb = *(const float4*)&bias[gcol];
        ushort4 r = *(const ushort4*)&resb[idx];
        o0 += bb.x + bf2f(r.x); o1 += bb.y + bf2f(r.y);
        o2 += bb.z + bf2f(r.z); o3 += bb.w + bf2f(r.w);
      }
      ushort4 o;
      o.x = f2bf(o0); o.y = f2bf(o1); o.z = f2bf(o2); o.w = f2bf(o3);
      *(ushort4*)&Cout[idx] = o;
    }
  }
}

// ---------------- row softmax (in-place bf16): P = softmax(S) ---------------
__global__ __launch_bounds__(256) void softmax_kernel(unsigned short* __restrict__ S) {
  __shared__ float red[4];
  const size_t row = blockIdx.x;
  const int t = threadIdx.x;
  ushort4 u = *(const ushort4*)(S + row * 1024 + t * 4);
  float v0 = bf2f(u.x), v1 = bf2f(u.y), v2 = bf2f(u.z), v3 = bf2f(u.w);
  float mx = fmaxf(fmaxf(v0, v1), fmaxf(v2, v3));
#pragma unroll
  for (int o = 32; o; o >>= 1) mx = fmaxf(mx, __shfl_xor(mx, o));
  if ((t & 63) == 0) red[t >> 6] = mx;
  __syncthreads();
  mx = fmaxf(fmaxf(red[0], red[1]), fmaxf(red[2], red[3]));
  __syncthreads();
  float e0 = __expf(v0 - mx), e1 = __expf(v1 - mx);
  float e2 = __expf(v2 - mx), e3 = __expf(v3 - mx);
  float s = e0 + e1 + e2 + e3;
#pragma unroll
  for (int o = 32; o; o >>= 1) s += __shfl_xor(s, o);
  if ((t & 63) == 0) red[t >> 6] = s;
  __syncthreads();
  s = red[0] + red[1] + red[2] + red[3];
  const float inv = 1.f / s;
  ushort4 o4;
  o4.x = f2bf(e0 * inv); o4.y = f2bf(e1 * inv);
  o4.z = f2bf(e2 * inv); o4.w = f2bf(e3 * inv);
  *(ushort4*)(S + row * 1024 + t * 4) = o4;
}

// ---------------- LayerNorm over rows of 1024, bf16 input -------------------
// out = LN(A_bf16); writes fp32 (Xf) and/or bf16 (Xb).
__global__ __launch_bounds__(256) void ln_bf_kernel(
    const unsigned short* __restrict__ A,
    const float* __restrict__ gamma, const float* __restrict__ beta,
    float* __restrict__ Xf, unsigned short* __restrict__ Xb) {
  __shared__ float red[4];
  const size_t row = blockIdx.x;
  const int t = threadIdx.x;
  ushort4 ua = *(const ushort4*)(A + row * 1024 + t * 4);
  float x0 = bf2f(ua.x), x1 = bf2f(ua.y), x2 = bf2f(ua.z), x3 = bf2f(ua.w);
  float s = x0 + x1 + x2 + x3;
  float q = x0 * x0 + x1 * x1 + x2 * x2 + x3 * x3;
#pragma unroll
  for (int o = 32; o; o >>= 1) { s += __shfl_xor(s, o); q += __shfl_xor(q, o); }
  if ((t & 63) == 0) red[t >> 6] = s;
  __syncthreads();
  s = red[0] + red[1] + red[2] + red[3];
  __syncthreads();
  if ((t & 63) == 0) red[t >> 6] = q;
  __syncthreads();
  q = red[0] + red[1] + red[2] + red[3];
  const float mu = s * (1.f / 1024.f);
  const float var = q * (1.f / 1024.f) - mu * mu;
  const float rs = rsqrtf(var + 1e-5f);
  float4 g = *(const float4*)(gamma + t * 4);
  float4 be = *(const float4*)(beta + t * 4);
  float o0 = (x0 - mu) * rs * g.x + be.x;
  float o1 = (x1 - mu) * rs * g.y + be.y;
  float o2 = (x2 - mu) * rs * g.z + be.z;
  float o3 = (x3 - mu) * rs * g.w + be.w;
  if (Xf) {
    float4 o; o.x = o0; o.y = o1; o.z = o2; o.w = o3;
    *(float4*)(Xf + row * 1024 + t * 4) = o;
  }
  if (Xb) {
    ushort4 u; u.x = f2bf(o0); u.y = f2bf(o1); u.z = f2bf(o2); u.w = f2bf(o3);
    *(ushort4*)(Xb + row * 1024 + t * 4) = u;
  }
}

// ---------------------------------------------------------------------------
extern "C" void kernel_launch(void* const* d_in, const int* in_sizes, int n_in,
                              void* d_out, int out_size, void* d_ws, size_t ws_size,
                              hipStream_t stream) {
  const float* Q    = (const float*)d_in[0];
  const float* Km   = (const float*)d_in[1];
  const float* V    = (const float*)d_in[2];
  const float* W1   = (const float*)d_in[3];
  const float* b1   = (const float*)d_in[4];
  const float* W2   = (const float*)d_in[5];
  const float* b2   = (const float*)d_in[6];
  const float* gamma = (const float*)d_in[7];
  const float* beta  = (const float*)d_in[8];
  float* out = (float*)d_out;

  // workspace (bf16 planes of 64MB = 32M elements):
  //  Qb, Kb, Vtb, Sb(->P, ->Hb), VAb(->Fb), Xb, W1b, W2b
  char* ws = (char*)d_ws;
  const size_t NEL = (size_t)32 * 1024 * 1024;
  unsigned short* Qb  = (unsigned short*)ws;
  unsigned short* Kb  = Qb + NEL;
  unsigned short* Vtb = Kb + NEL;
  unsigned short* Sb  = Vtb + NEL;
  unsigned short* VAb = Sb + NEL;
  unsigned short* Xb  = VAb + NEL;
  unsigned short* W1b = Xb + NEL;
  unsigned short* W2b = W1b + 1024 * 1024;
  unsigned short* Hb  = Sb;    // alias: P dead after GEMM2
  unsigned short* Fb  = VAb;   // alias: VAb dead after ln1

  const long M1 = 1024L * 1024L;
  const float scale = 1.0f / (sqrtf(1024.0f) + 1e-8f);

  cast_kernel<<<4096, 256, 0, stream>>>(Q, Qb, (long)NEL);
  cast_kernel<<<4096, 256, 0, stream>>>(Km, Kb, (long)NEL);
  cast_kernel<<<64, 256, 0, stream>>>(W1, W1b, 1024 * 1024);
  cast_kernel<<<64, 256, 0, stream>>>(W2, W2b, 1024 * 1024);
  transpose_cast_kernel<<<dim3(32, 32, 32), 256, 0, stream>>>(V, Vtb);

  // Sb = bf16((Q K^T) * scale)    [grid 4x4x32 = 512]
  gemm8<4><<<512, 512, 0, stream>>>(Qb, Kb, nullptr, nullptr, Sb,
                                    1024, 1024, M1, M1, M1, scale, 4, 16);
  softmax_kernel<<<32768, 256, 0, stream>>>(Sb);
  // VAb = bf16(P @ Vt^T + Qb)     (residual fused, bf16)
  gemm8<6><<<512, 512, 0, stream>>>(Sb, Vtb, nullptr, Qb, VAb,
                                    1024, 1024, M1, M1, M1, 1.0f, 4, 16);
  // Xb = bf16(LN(VAb))
  ln_bf_kernel<<<32768, 256, 0, stream>>>(VAb, gamma, beta, nullptr, Xb);
  // Hb = bf16(relu(Xb @ W1^T + b1))   [M=32768: grid 4x128]
  gemm8<2><<<512, 512, 0, stream>>>(Xb, W1b, b1, nullptr, Hb,
                                    1024, 1024, 0, 0, 0, 1.0f, 4, 512);
  // Fb = bf16(Hb @ W2^T + b2 + Xb)    (residual fused)
  gemm8<7><<<512, 512, 0, stream>>>(Hb, W2b, b2, Xb, Fb,
                                    1024, 1024, 0, 0, 0, 1.0f, 4, 512);
  // out = LN(Fb)  (fp32 final)
  ln_bf_kernel<<<32768, 256, 0, stream>>>(Fb, gamma, beta, out, nullptr);
}